// Round 8
// baseline (519.784 us; speedup 1.0000x reference)
//
#include <hip/hip_runtime.h>

#define NWIN 49
#define CDIM 128
#define SCALEQ 0.17677669529663687f

typedef _Float16 half8 __attribute__((ext_vector_type(8)));
typedef _Float16 half4v __attribute__((ext_vector_type(4)));
typedef float f32x4 __attribute__((ext_vector_type(4)));

// ---- d_ws f16 layout (element offsets) ----
#define WS_WQKV  0        // [384][128] f16, q-rows (n<128) pre-scaled by SCALEQ
#define WS_WPROJ 49152    // [128][128] f16
#define WS_BQKV  65536    // [384] f16 (q part pre-scaled)
#define WS_BIAS  65920    // [4][49][64] f16: bias[h][q][key], key>=49 -> -1e4
#define WS_TOTAL 78464    // halves

// ---- LDS strides (halves) ----
#define XL_STR 136        // x / O tile row stride (272 B)
#define QK_STR 40         // Q,K row stride (80 B)
#define P_STR  72         // P row stride (144 B); cols 64..67 hold f32 partial sums

#define XBUF_H  (NWIN * XL_STR)    // 6664 halves: x, later O
#define K_OFF_H (NWIN * QK_STR)    // 1960: K after Q
#define HEAD_H  (2 * K_OFF_H)      // 3920 per head (P overlays Q|K: 49*72=3528 <= 3920)
#define SMEM_H  (XBUF_H + 4 * HEAD_H)  // 22344 halves = 44688 B -> 3 blocks/CU

__global__ __launch_bounds__(256)
void prepack(const float* __restrict__ w_qkv, const float* __restrict__ b_qkv,
             const float* __restrict__ w_proj, const float* __restrict__ bias_table,
             const int* __restrict__ rel_index, _Float16* __restrict__ ws)
{
    int i = blockIdx.x * 256 + threadIdx.x;
    if (i < 49152) {
        float v = w_qkv[i];
        if (i < 16384) v *= SCALEQ;          // q rows (n<128)
        ws[WS_WQKV + i] = (_Float16)v;
    } else if (i < 65536) {
        ws[i] = (_Float16)w_proj[i - 49152];
    } else if (i < 65920) {
        int n = i - 65536;
        float v = b_qkv[n];
        if (n < 128) v *= SCALEQ;
        ws[WS_BQKV + n] = (_Float16)v;
    } else if (i < WS_TOTAL) {
        int t = i - 65920;
        int h = t / 3136;                    // 49*64
        int r = t - h * 3136;
        int q = r >> 6;
        int key = r & 63;
        float v = (key < 49) ? bias_table[(size_t)rel_index[q * 49 + key] * 4 + h]
                             : -1e4f;
        ws[WS_BIAS + t] = (_Float16)v;
    }
}

// 512 threads = 8 waves: wave = (head h = w>>1, col-half c = w&1).
// Single x buffer (reg-staged T14), V kept in registers via ds_bpermute
// redistribution, sums in P pad -> 44.7 KB LDS -> 3 blocks/CU target.
__global__ __launch_bounds__(512)
void lwa_fused(const float* __restrict__ x, const _Float16* __restrict__ ws,
               const float* __restrict__ b_proj, float* __restrict__ out,
               int nwin_total, int wpb)
{
    __shared__ __align__(16) _Float16 smem[SMEM_H];

    const int tid  = threadIdx.x;
    const int w    = tid >> 6;
    const int h    = w >> 1;
    const int c    = w & 1;
    const int lane = tid & 63;
    const int lo   = lane & 15;
    const int hi   = lane >> 4;
    const int ncol = 32 * h + 16 * c + lo;

    _Float16* const xb = smem;                       // x, later O (49 x 136)
    _Float16* const Qh = smem + XBUF_H + h * HEAD_H; // 49 x 32, stride 40
    _Float16* const Kh = Qh + K_OFF_H;               // 49 x 32, stride 40
    _Float16* const Ph = Qh;                         // overlay: 49 x 64 (+sums pad), stride 72

    const float bp = b_proj[ncol];
    const f32x4 zf = {0.f, 0.f, 0.f, 0.f};

    // V-shuffle source byte-addrs: src lane = lo + 32*(hi&1) (and +16)
    const int srcA = (((lane & 15) | ((lane & 16) << 1)) << 2);
    const int srcB = srcA + 64;

    const int r0 = tid >> 4;            // 0..31
    const int gc = (tid & 15) * 8;

    int b0 = blockIdx.x * wpb;
    int b1 = b0 + wpb; if (b1 > nwin_total) b1 = nwin_total;

    // ---------- prologue: stage x[b0] ----------
    {
        const float* xs = x + (size_t)b0 * NWIN * CDIM;
#pragma unroll
        for (int p = 0; p < 2; ++p) {
            int row = r0 + p * 32;
            if (row < 49) {
                const float* sp = xs + (size_t)row * CDIM + gc;
                float4 u0 = *reinterpret_cast<const float4*>(sp);
                float4 u1 = *reinterpret_cast<const float4*>(sp + 4);
                half8 hh;
                hh[0] = (_Float16)u0.x; hh[1] = (_Float16)u0.y;
                hh[2] = (_Float16)u0.z; hh[3] = (_Float16)u0.w;
                hh[4] = (_Float16)u1.x; hh[5] = (_Float16)u1.y;
                hh[6] = (_Float16)u1.z; hh[7] = (_Float16)u1.w;
                *reinterpret_cast<half8*>(&xb[row * XL_STR + gc]) = hh;
            }
        }
    }
    __syncthreads();   // B0: x visible

    for (int b = b0; b < b1; ++b) {
        const bool hn = (b + 1 < b1);

        // ---- T14 issue-early: next-window x -> registers ----
        float4 s0a, s0b, s1a, s1b;
        if (hn) {
            const float* xs = x + (size_t)(b + 1) * NWIN * CDIM;
            const float* sp0 = xs + (size_t)r0 * CDIM + gc;
            s0a = *reinterpret_cast<const float4*>(sp0);
            s0b = *reinterpret_cast<const float4*>(sp0 + 4);
            int row1 = r0 + 32;
            if (row1 < 49) {
                const float* sp1 = xs + (size_t)row1 * CDIM + gc;
                s1a = *reinterpret_cast<const float4*>(sp1);
                s1b = *reinterpret_cast<const float4*>(sp1 + 4);
            }
        }

        // ---- GEMM1: q,k -> LDS; v -> registers via bpermute redistribution ----
        int4 vf0i = {0, 0, 0, 0}, vf1i = {0, 0, 0, 0};
#pragma unroll 1
        for (int tn = 0; tn < 3; ++tn) {
            const _Float16* wbp = ws + WS_WQKV + ((size_t)(tn * CDIM + ncol)) * CDIM + hi * 8;
            half8 wf0 = *reinterpret_cast<const half8*>(wbp);
            half8 wf1 = *reinterpret_cast<const half8*>(wbp + 32);
            half8 wf2 = *reinterpret_cast<const half8*>(wbp + 64);
            half8 wf3 = *reinterpret_cast<const half8*>(wbp + 96);
            float bqv = (float)ws[WS_BQKV + tn * CDIM + ncol];
#pragma unroll 1
            for (int tm = 0; tm < 4; ++tm) {
                int ar = 16 * tm + lo; if (ar > 48) ar = 48;
                const _Float16* ap = &xb[ar * XL_STR + hi * 8];
                half8 a0 = *reinterpret_cast<const half8*>(ap);
                half8 a1 = *reinterpret_cast<const half8*>(ap + 32);
                half8 a2 = *reinterpret_cast<const half8*>(ap + 64);
                half8 a3 = *reinterpret_cast<const half8*>(ap + 96);
                f32x4 acc; acc[0] = bqv; acc[1] = bqv; acc[2] = bqv; acc[3] = bqv;
                acc = __builtin_amdgcn_mfma_f32_16x16x32_f16(a0, wf0, acc, 0, 0, 0);
                acc = __builtin_amdgcn_mfma_f32_16x16x32_f16(a1, wf1, acc, 0, 0, 0);
                acc = __builtin_amdgcn_mfma_f32_16x16x32_f16(a2, wf2, acc, 0, 0, 0);
                acc = __builtin_amdgcn_mfma_f32_16x16x32_f16(a3, wf3, acc, 0, 0, 0);
                if (tn == 2) {
                    // v rows 16tm+4hi+j, col 16c+lo -> redistribute to PV A-frag:
                    // consumer (hi,kk=tm>>1) needs tokens kk*32+8hi+e from
                    // src lanes lo+32(hi&1) (e0..3) and +16 (e4..7), tile tm=2kk+(hi>>1).
                    half4v hv;
#pragma unroll
                    for (int j = 0; j < 4; ++j) hv[j] = (_Float16)acc[j];
                    int2 vd = __builtin_bit_cast(int2, hv);
                    int d0 = __builtin_amdgcn_ds_bpermute(srcA, vd.x);
                    int d1 = __builtin_amdgcn_ds_bpermute(srcA, vd.y);
                    int d2 = __builtin_amdgcn_ds_bpermute(srcB, vd.x);
                    int d3 = __builtin_amdgcn_ds_bpermute(srcB, vd.y);
                    bool take = ((hi >> 1) == (tm & 1));
                    if (tm < 2) {
                        vf0i.x = take ? d0 : vf0i.x; vf0i.y = take ? d1 : vf0i.y;
                        vf0i.z = take ? d2 : vf0i.z; vf0i.w = take ? d3 : vf0i.w;
                    } else {
                        vf1i.x = take ? d0 : vf1i.x; vf1i.y = take ? d1 : vf1i.y;
                        vf1i.z = take ? d2 : vf1i.z; vf1i.w = take ? d3 : vf1i.w;
                    }
                } else {
                    _Float16* dst = (tn == 0) ? Qh : Kh;
#pragma unroll
                    for (int j = 0; j < 4; ++j) {
                        int row = 16 * tm + 4 * hi + j;
                        if (row < 49) dst[row * QK_STR + 16 * c + lo] = (_Float16)acc[j];
                    }
                }
            }
        }
        __syncthreads();  // B1: Q,K visible; xb (x) dead -> becomes O region

        // ---- hoist K,Q fragment reads (P overlays Q|K) ----
        half8 kf[2], qf[4];
#pragma unroll
        for (int kt = 0; kt < 2; ++kt) {
            int kr = 16 * (2 * c + kt) + lo; if (kr > 48) kr = 48;
            kf[kt] = *reinterpret_cast<const half8*>(&Kh[kr * QK_STR + hi * 8]);
        }
#pragma unroll
        for (int t = 0; t < 4; ++t)
            qf[t] = *reinterpret_cast<const half8*>(&Qh[(16 * t + lo) * QK_STR + hi * 8]);
        __syncthreads();  // B2: Q/K reads done -> P region writable

        // ---- S^T slice, exp, P stores, partial sums into P pad ----
#pragma unroll
        for (int tnq = 0; tnq < 4; ++tnq) {
            int q = 16 * tnq + lo;
            int qc = (q < 49) ? q : 48;
            const _Float16* bb = ws + WS_BIAS + ((size_t)h * 49 + qc) * 64 + 32 * c + 4 * hi;
            float sum = 0.f;
#pragma unroll
            for (int kt = 0; kt < 2; ++kt) {
                f32x4 s = __builtin_amdgcn_mfma_f32_16x16x32_f16(kf[kt], qf[tnq], zf, 0, 0, 0);
                half4v bt = *reinterpret_cast<const half4v*>(bb + kt * 16);
                half4v hv;
#pragma unroll
                for (int j = 0; j < 4; ++j) {
                    float pv = __expf(s[j] + (float)bt[j]);
                    sum += pv;
                    hv[j] = (_Float16)pv;
                }
                if (q < 49)
                    *reinterpret_cast<half4v*>(&Ph[q * P_STR + 32 * c + 16 * kt + 4 * hi]) = hv;
            }
            sum += __shfl_xor(sum, 16);
            sum += __shfl_xor(sum, 32);
            if (hi == 0 && q < 49)
                *reinterpret_cast<float*>(&Ph[q * P_STR + 64 + 2 * c]) = sum;
        }
        __syncthreads();  // B3: P + sums visible

        // ---- PV: O^T slice from register V-frags; normalized O -> xb ----
        {
            half8 vf0 = __builtin_bit_cast(half8, vf0i);
            half8 vf1 = __builtin_bit_cast(half8, vf1i);
#pragma unroll
            for (int tnq = 0; tnq < 4; ++tnq) {
                int q = 16 * tnq + lo;
                int qr = (q < 49) ? q : 48;
                half8 pf0 = *reinterpret_cast<const half8*>(&Ph[qr * P_STR + hi * 8]);
                half8 pf1 = *reinterpret_cast<const half8*>(&Ph[qr * P_STR + 32 + hi * 8]);
                f32x4 o = __builtin_amdgcn_mfma_f32_16x16x32_f16(vf0, pf0, zf, 0, 0, 0);
                o = __builtin_amdgcn_mfma_f32_16x16x32_f16(vf1, pf1, o, 0, 0, 0);
                if (q < 49) {
                    float2 s2 = *reinterpret_cast<const float2*>(&Ph[q * P_STR + 64]);
                    float invl = 1.0f / (s2.x + s2.y);
                    half4v hv;
#pragma unroll
                    for (int j = 0; j < 4; ++j) hv[j] = (_Float16)(o[j] * invl);
                    *reinterpret_cast<half4v*>(&xb[q * XL_STR + 32 * h + 16 * c + 4 * hi]) = hv;
                }
            }
        }
        __syncthreads();  // B4: O complete

        // ---- GEMM3: out = O @ w_proj^T + b_proj ----
        {
            const _Float16* wpp = ws + WS_WPROJ + (size_t)ncol * CDIM + hi * 8;
            half8 p0 = *reinterpret_cast<const half8*>(wpp);
            half8 p1 = *reinterpret_cast<const half8*>(wpp + 32);
            half8 p2 = *reinterpret_cast<const half8*>(wpp + 64);
            half8 p3 = *reinterpret_cast<const half8*>(wpp + 96);
#pragma unroll 1
            for (int tm = 0; tm < 4; ++tm) {
                int orr = 16 * tm + lo; if (orr > 48) orr = 48;
                const _Float16* op = &xb[orr * XL_STR + hi * 8];
                half8 oa0 = *reinterpret_cast<const half8*>(op);
                half8 oa1 = *reinterpret_cast<const half8*>(op + 32);
                half8 oa2 = *reinterpret_cast<const half8*>(op + 64);
                half8 oa3 = *reinterpret_cast<const half8*>(op + 96);
                f32x4 g; g[0] = bp; g[1] = bp; g[2] = bp; g[3] = bp;
                g = __builtin_amdgcn_mfma_f32_16x16x32_f16(oa0, p0, g, 0, 0, 0);
                g = __builtin_amdgcn_mfma_f32_16x16x32_f16(oa1, p1, g, 0, 0, 0);
                g = __builtin_amdgcn_mfma_f32_16x16x32_f16(oa2, p2, g, 0, 0, 0);
                g = __builtin_amdgcn_mfma_f32_16x16x32_f16(oa3, p3, g, 0, 0, 0);
#pragma unroll
                for (int j = 0; j < 4; ++j) {
                    int row = 16 * tm + 4 * hi + j;
                    if (row < 49)
                        out[((size_t)b * NWIN + row) * CDIM + ncol] = g[j];
                }
            }
        }
        __syncthreads();  // B5: O reads done -> xb writable as next x

        // ---- T14 write-late: next-window x regs -> LDS ----
        if (hn) {
            half8 hh;
            hh[0] = (_Float16)s0a.x; hh[1] = (_Float16)s0a.y;
            hh[2] = (_Float16)s0a.z; hh[3] = (_Float16)s0a.w;
            hh[4] = (_Float16)s0b.x; hh[5] = (_Float16)s0b.y;
            hh[6] = (_Float16)s0b.z; hh[7] = (_Float16)s0b.w;
            *reinterpret_cast<half8*>(&xb[r0 * XL_STR + gc]) = hh;
            int row1 = r0 + 32;
            if (row1 < 49) {
                half8 h2;
                h2[0] = (_Float16)s1a.x; h2[1] = (_Float16)s1a.y;
                h2[2] = (_Float16)s1a.z; h2[3] = (_Float16)s1a.w;
                h2[4] = (_Float16)s1b.x; h2[5] = (_Float16)s1b.y;
                h2[6] = (_Float16)s1b.z; h2[7] = (_Float16)s1b.w;
                *reinterpret_cast<half8*>(&xb[row1 * XL_STR + gc]) = h2;
            }
        }
        __syncthreads();  // B0': next x visible
    }
}

extern "C" void kernel_launch(void* const* d_in, const int* in_sizes, int n_in,
                              void* d_out, int out_size, void* d_ws, size_t ws_size,
                              hipStream_t stream) {
    const float* x          = (const float*)d_in[0];
    // d_in[1] = q_global: unused by the reference
    const float* w_qkv      = (const float*)d_in[2];
    const float* b_qkv      = (const float*)d_in[3];
    const float* w_proj     = (const float*)d_in[4];
    const float* b_proj     = (const float*)d_in[5];
    const float* bias_table = (const float*)d_in[6];
    const int*   rel_index  = (const int*)d_in[7];

    _Float16* ws = (_Float16*)d_ws;

    prepack<<<(WS_TOTAL + 255) / 256, 256, 0, stream>>>(w_qkv, b_qkv, w_proj,
                                                        bias_table, rel_index, ws);

    const int nwin = in_sizes[0] / (NWIN * CDIM);   // 16384
    const int wpb = 8;
    const int nblk = (nwin + wpb - 1) / wpb;        // 2048

    lwa_fused<<<nblk, 512, 0, stream>>>(x, ws, b_proj, (float*)d_out,
                                        nwin, wpb);
}

// Round 9
// 384.086 us; speedup vs baseline: 1.3533x; 1.3533x over previous
//
#include <hip/hip_runtime.h>

#define NWIN 49
#define CDIM 128
#define SCALEQ 0.17677669529663687f

typedef _Float16 half8 __attribute__((ext_vector_type(8)));
typedef _Float16 half4v __attribute__((ext_vector_type(4)));
typedef float f32x4 __attribute__((ext_vector_type(4)));

// ---- d_ws f16 layout (element offsets) ----
#define WS_WQKV  0        // [384][128] f16, q-rows (n<128) pre-scaled by SCALEQ
#define WS_WPROJ 49152    // [128][128] f16
#define WS_BQKV  65536    // [384] f16 (q part pre-scaled)
#define WS_BIAS  65920    // [4][49][64] f16: bias[h][q][key], key>=49 -> -1e4
#define WS_TOTAL 78464    // halves

// ---- LDS strides (halves) ----
#define XL_STR 136        // x / O tile row stride (272 B)
#define QK_STR 40         // Q,K row stride (80 B)
#define P_STR  72         // P row stride (144 B); cols 64..67 hold f32 partial sums

// 64-row padded regions: epilogues write rows 0..63 unconditionally (rows 49..63
// are duplicates of row 48 — finite, never consumed), killing ~100 predicated
// VALU ops per wave-window.
#define XBUF_H  (64 * XL_STR)          // 8704 halves: x, later O
#define K_OFF_H (64 * QK_STR)          // 2560: K after Q
#define HEAD_H  (2 * K_OFF_H)          // 5120 per head (P overlay 64*72=4608 <= 5120)
#define SMEM_H  (XBUF_H + 4 * HEAD_H)  // 29184 halves = 58368 B -> 2 blocks/CU

__global__ __launch_bounds__(256)
void prepack(const float* __restrict__ w_qkv, const float* __restrict__ b_qkv,
             const float* __restrict__ w_proj, const float* __restrict__ bias_table,
             const int* __restrict__ rel_index, _Float16* __restrict__ ws)
{
    int i = blockIdx.x * 256 + threadIdx.x;
    if (i < 49152) {
        float v = w_qkv[i];
        if (i < 16384) v *= SCALEQ;          // q rows (n<128)
        ws[WS_WQKV + i] = (_Float16)v;
    } else if (i < 65536) {
        ws[i] = (_Float16)w_proj[i - 49152];
    } else if (i < 65920) {
        int n = i - 65536;
        float v = b_qkv[n];
        if (n < 128) v *= SCALEQ;
        ws[WS_BQKV + n] = (_Float16)v;
    } else if (i < WS_TOTAL) {
        int t = i - 65920;
        int h = t / 3136;                    // 49*64
        int r = t - h * 3136;
        int q = r >> 6;
        int key = r & 63;
        float v = (key < 49) ? bias_table[(size_t)rel_index[q * 49 + key] * 4 + h]
                             : -1e4f;
        ws[WS_BIAS + t] = (_Float16)v;
    }
}

// 512 threads = 8 waves: wave = (head h = w>>1, col-half c = w&1).
// GEMM1: tm-outer rolled, q/k/v unrolled inside -> x A-frags read ONCE (16
// ds_read_b128/wave/window instead of 48). Weights streamed per window into
// transient regs. V stays in registers (bpermute). T14 reg staging.
__global__ __launch_bounds__(512)
void lwa_fused(const float* __restrict__ x, const _Float16* __restrict__ ws,
               const float* __restrict__ b_proj, float* __restrict__ out,
               int nwin_total, int wpb)
{
    __shared__ __align__(16) _Float16 smem[SMEM_H];

    const int tid  = threadIdx.x;
    const int w    = tid >> 6;
    const int h    = w >> 1;
    const int c    = w & 1;
    const int lane = tid & 63;
    const int lo   = lane & 15;
    const int hi   = lane >> 4;
    const int ncol = 32 * h + 16 * c + lo;

    _Float16* const xb = smem;                       // x, later O (64 x 136)
    _Float16* const Qh = smem + XBUF_H + h * HEAD_H; // 64 x 32, stride 40
    _Float16* const Kh = Qh + K_OFF_H;               // 64 x 32, stride 40
    _Float16* const Ph = Qh;                         // overlay: 64 x 64 (+sums pad), stride 72

    const float bp = b_proj[ncol];
    const f32x4 zf = {0.f, 0.f, 0.f, 0.f};

    // V-shuffle source byte-addrs: src lane = lo + 32*(hi&1) (and +16)
    const int srcA = (((lane & 15) | ((lane & 16) << 1)) << 2);
    const int srcB = srcA + 64;

    const int r0 = tid >> 4;            // 0..31
    const int gc = (tid & 15) * 8;

    int b0 = blockIdx.x * wpb;
    int b1 = b0 + wpb; if (b1 > nwin_total) b1 = nwin_total;

    // ---------- prologue: stage x[b0] ----------
    {
        const float* xs = x + (size_t)b0 * NWIN * CDIM;
#pragma unroll
        for (int p = 0; p < 2; ++p) {
            int row = r0 + p * 32;
            if (row < 49) {
                const float* sp = xs + (size_t)row * CDIM + gc;
                float4 u0 = *reinterpret_cast<const float4*>(sp);
                float4 u1 = *reinterpret_cast<const float4*>(sp + 4);
                half8 hh;
                hh[0] = (_Float16)u0.x; hh[1] = (_Float16)u0.y;
                hh[2] = (_Float16)u0.z; hh[3] = (_Float16)u0.w;
                hh[4] = (_Float16)u1.x; hh[5] = (_Float16)u1.y;
                hh[6] = (_Float16)u1.z; hh[7] = (_Float16)u1.w;
                *reinterpret_cast<half8*>(&xb[row * XL_STR + gc]) = hh;
            }
        }
    }
    __syncthreads();   // B0: x visible

    for (int b = b0; b < b1; ++b) {
        const bool hn = (b + 1 < b1);

        // ---- T14 issue-early: next-window x -> registers ----
        float4 s0a, s0b, s1a, s1b;
        if (hn) {
            const float* xs = x + (size_t)(b + 1) * NWIN * CDIM;
            const float* sp0 = xs + (size_t)r0 * CDIM + gc;
            s0a = *reinterpret_cast<const float4*>(sp0);
            s0b = *reinterpret_cast<const float4*>(sp0 + 4);
            int row1 = r0 + 32;
            if (row1 < 49) {
                const float* sp1 = xs + (size_t)row1 * CDIM + gc;
                s1a = *reinterpret_cast<const float4*>(sp1);
                s1b = *reinterpret_cast<const float4*>(sp1 + 4);
            }
        }

        // ---- GEMM1 weight preload (transient ~51 VGPR, live only this phase) ----
        half8 wf0[4], wf1[4], wf2[4];
        {
            const _Float16* wp0 = ws + WS_WQKV + (size_t)ncol * CDIM + hi * 8;
            const _Float16* wp1 = wp0 + (size_t)CDIM * CDIM;
            const _Float16* wp2 = wp1 + (size_t)CDIM * CDIM;
#pragma unroll
            for (int kk = 0; kk < 4; ++kk) {
                wf0[kk] = *reinterpret_cast<const half8*>(wp0 + kk * 32);
                wf1[kk] = *reinterpret_cast<const half8*>(wp1 + kk * 32);
                wf2[kk] = *reinterpret_cast<const half8*>(wp2 + kk * 32);
            }
        }
        float bq0 = (float)ws[WS_BQKV + ncol];
        float bq1 = (float)ws[WS_BQKV + CDIM + ncol];
        float bq2 = (float)ws[WS_BQKV + 2 * CDIM + ncol];

        // ---- GEMM1: x A-frags read once; q,k -> LDS (unconditional), v -> regs ----
        int4 vf0i = {0, 0, 0, 0}, vf1i = {0, 0, 0, 0};
#pragma unroll 1
        for (int tm = 0; tm < 4; ++tm) {
            int ar = 16 * tm + lo; if (ar > 48) ar = 48;
            const _Float16* ap = &xb[ar * XL_STR + hi * 8];
            half8 a0 = *reinterpret_cast<const half8*>(ap);
            half8 a1 = *reinterpret_cast<const half8*>(ap + 32);
            half8 a2 = *reinterpret_cast<const half8*>(ap + 64);
            half8 a3 = *reinterpret_cast<const half8*>(ap + 96);

            f32x4 aq; aq[0] = bq0; aq[1] = bq0; aq[2] = bq0; aq[3] = bq0;
            aq = __builtin_amdgcn_mfma_f32_16x16x32_f16(a0, wf0[0], aq, 0, 0, 0);
            aq = __builtin_amdgcn_mfma_f32_16x16x32_f16(a1, wf0[1], aq, 0, 0, 0);
            aq = __builtin_amdgcn_mfma_f32_16x16x32_f16(a2, wf0[2], aq, 0, 0, 0);
            aq = __builtin_amdgcn_mfma_f32_16x16x32_f16(a3, wf0[3], aq, 0, 0, 0);

            f32x4 ak; ak[0] = bq1; ak[1] = bq1; ak[2] = bq1; ak[3] = bq1;
            ak = __builtin_amdgcn_mfma_f32_16x16x32_f16(a0, wf1[0], ak, 0, 0, 0);
            ak = __builtin_amdgcn_mfma_f32_16x16x32_f16(a1, wf1[1], ak, 0, 0, 0);
            ak = __builtin_amdgcn_mfma_f32_16x16x32_f16(a2, wf1[2], ak, 0, 0, 0);
            ak = __builtin_amdgcn_mfma_f32_16x16x32_f16(a3, wf1[3], ak, 0, 0, 0);

            f32x4 av; av[0] = bq2; av[1] = bq2; av[2] = bq2; av[3] = bq2;
            av = __builtin_amdgcn_mfma_f32_16x16x32_f16(a0, wf2[0], av, 0, 0, 0);
            av = __builtin_amdgcn_mfma_f32_16x16x32_f16(a1, wf2[1], av, 0, 0, 0);
            av = __builtin_amdgcn_mfma_f32_16x16x32_f16(a2, wf2[2], av, 0, 0, 0);
            av = __builtin_amdgcn_mfma_f32_16x16x32_f16(a3, wf2[3], av, 0, 0, 0);

            // epilogue: Q,K scalar f16 rows 0..63 unconditional (pad rows unread)
#pragma unroll
            for (int j = 0; j < 4; ++j) {
                int row = 16 * tm + 4 * hi + j;
                Qh[row * QK_STR + 16 * c + lo] = (_Float16)aq[j];
                Kh[row * QK_STR + 16 * c + lo] = (_Float16)ak[j];
            }
            // v -> PV A-frag via bpermute redistribution (r8-verified)
            half4v hv;
#pragma unroll
            for (int j = 0; j < 4; ++j) hv[j] = (_Float16)av[j];
            int2 vd = __builtin_bit_cast(int2, hv);
            int d0 = __builtin_amdgcn_ds_bpermute(srcA, vd.x);
            int d1 = __builtin_amdgcn_ds_bpermute(srcA, vd.y);
            int d2 = __builtin_amdgcn_ds_bpermute(srcB, vd.x);
            int d3 = __builtin_amdgcn_ds_bpermute(srcB, vd.y);
            bool take = ((hi >> 1) == (tm & 1));
            if (tm < 2) {
                vf0i.x = take ? d0 : vf0i.x; vf0i.y = take ? d1 : vf0i.y;
                vf0i.z = take ? d2 : vf0i.z; vf0i.w = take ? d3 : vf0i.w;
            } else {
                vf1i.x = take ? d0 : vf1i.x; vf1i.y = take ? d1 : vf1i.y;
                vf1i.z = take ? d2 : vf1i.z; vf1i.w = take ? d3 : vf1i.w;
            }
        }
        __syncthreads();  // B1: Q,K visible; xb (x) dead -> becomes O region

        // ---- hoist K,Q fragment reads (P overlays Q|K); rows<=63 valid, no clamps ----
        half8 kf[2], qf[4];
#pragma unroll
        for (int kt = 0; kt < 2; ++kt)
            kf[kt] = *reinterpret_cast<const half8*>(&Kh[(16 * (2 * c + kt) + lo) * QK_STR + hi * 8]);
#pragma unroll
        for (int t = 0; t < 4; ++t)
            qf[t] = *reinterpret_cast<const half8*>(&Qh[(16 * t + lo) * QK_STR + hi * 8]);
        __syncthreads();  // B2: Q/K reads done -> P region writable

        // ---- S^T slice, exp, P stores (unconditional), partial sums into P pad ----
#pragma unroll
        for (int tnq = 0; tnq < 4; ++tnq) {
            int q = 16 * tnq + lo;
            int qc = (q < 49) ? q : 48;   // bias gather address must stay in-table
            const _Float16* bb = ws + WS_BIAS + ((size_t)h * 49 + qc) * 64 + 32 * c + 4 * hi;
            float sum = 0.f;
#pragma unroll
            for (int kt = 0; kt < 2; ++kt) {
                f32x4 s = __builtin_amdgcn_mfma_f32_16x16x32_f16(kf[kt], qf[tnq], zf, 0, 0, 0);
                half4v bt = *reinterpret_cast<const half4v*>(bb + kt * 16);
                half4v hv;
#pragma unroll
                for (int j = 0; j < 4; ++j) {
                    float pv = __expf(s[j] + (float)bt[j]);
                    sum += pv;
                    hv[j] = (_Float16)pv;
                }
                *reinterpret_cast<half4v*>(&Ph[q * P_STR + 32 * c + 16 * kt + 4 * hi]) = hv;
            }
            sum += __shfl_xor(sum, 16);
            sum += __shfl_xor(sum, 32);
            if (hi == 0)
                *reinterpret_cast<float*>(&Ph[q * P_STR + 64 + 2 * c]) = sum;
        }
        __syncthreads();  // B3: P + sums visible

        // ---- PV: O^T slice from register V-frags; normalized O -> xb (uncond) ----
        {
            half8 vf0 = __builtin_bit_cast(half8, vf0i);
            half8 vf1 = __builtin_bit_cast(half8, vf1i);
#pragma unroll
            for (int tnq = 0; tnq < 4; ++tnq) {
                int q = 16 * tnq + lo;
                half8 pf0 = *reinterpret_cast<const half8*>(&Ph[q * P_STR + hi * 8]);
                half8 pf1 = *reinterpret_cast<const half8*>(&Ph[q * P_STR + 32 + hi * 8]);
                f32x4 o = __builtin_amdgcn_mfma_f32_16x16x32_f16(vf0, pf0, zf, 0, 0, 0);
                o = __builtin_amdgcn_mfma_f32_16x16x32_f16(vf1, pf1, o, 0, 0, 0);
                float2 s2 = *reinterpret_cast<const float2*>(&Ph[q * P_STR + 64]);
                float invl = 1.0f / (s2.x + s2.y);
                half4v hv;
#pragma unroll
                for (int j = 0; j < 4; ++j) hv[j] = (_Float16)(o[j] * invl);
                *reinterpret_cast<half4v*>(&xb[q * XL_STR + 32 * h + 16 * c + 4 * hi]) = hv;
            }
        }
        __syncthreads();  // B4: O complete

        // ---- GEMM3: out = O @ w_proj^T + b_proj; unroll 2 for ds/MFMA overlap ----
        {
            const _Float16* wpp = ws + WS_WPROJ + (size_t)ncol * CDIM + hi * 8;
            half8 p0 = *reinterpret_cast<const half8*>(wpp);
            half8 p1 = *reinterpret_cast<const half8*>(wpp + 32);
            half8 p2 = *reinterpret_cast<const half8*>(wpp + 64);
            half8 p3 = *reinterpret_cast<const half8*>(wpp + 96);
#pragma unroll 2
            for (int tm = 0; tm < 4; ++tm) {
                int orr = 16 * tm + lo; if (orr > 48) orr = 48;
                const _Float16* op = &xb[orr * XL_STR + hi * 8];
                half8 oa0 = *reinterpret_cast<const half8*>(op);
                half8 oa1 = *reinterpret_cast<const half8*>(op + 32);
                half8 oa2 = *reinterpret_cast<const half8*>(op + 64);
                half8 oa3 = *reinterpret_cast<const half8*>(op + 96);
                f32x4 g; g[0] = bp; g[1] = bp; g[2] = bp; g[3] = bp;
                g = __builtin_amdgcn_mfma_f32_16x16x32_f16(oa0, p0, g, 0, 0, 0);
                g = __builtin_amdgcn_mfma_f32_16x16x32_f16(oa1, p1, g, 0, 0, 0);
                g = __builtin_amdgcn_mfma_f32_16x16x32_f16(oa2, p2, g, 0, 0, 0);
                g = __builtin_amdgcn_mfma_f32_16x16x32_f16(oa3, p3, g, 0, 0, 0);
#pragma unroll
                for (int j = 0; j < 4; ++j) {
                    int row = 16 * tm + 4 * hi + j;
                    if (row < 49)
                        out[((size_t)b * NWIN + row) * CDIM + ncol] = g[j];
                }
            }
        }
        __syncthreads();  // B5: O reads done -> xb writable as next x

        // ---- T14 write-late: next-window x regs -> LDS ----
        if (hn) {
            half8 hh;
            hh[0] = (_Float16)s0a.x; hh[1] = (_Float16)s0a.y;
            hh[2] = (_Float16)s0a.z; hh[3] = (_Float16)s0a.w;
            hh[4] = (_Float16)s0b.x; hh[5] = (_Float16)s0b.y;
            hh[6] = (_Float16)s0b.z; hh[7] = (_Float16)s0b.w;
            *reinterpret_cast<half8*>(&xb[r0 * XL_STR + gc]) = hh;
            int row1 = r0 + 32;
            if (row1 < 49) {
                half8 h2;
                h2[0] = (_Float16)s1a.x; h2[1] = (_Float16)s1a.y;
                h2[2] = (_Float16)s1a.z; h2[3] = (_Float16)s1a.w;
                h2[4] = (_Float16)s1b.x; h2[5] = (_Float16)s1b.y;
                h2[6] = (_Float16)s1b.z; h2[7] = (_Float16)s1b.w;
                *reinterpret_cast<half8*>(&xb[row1 * XL_STR + gc]) = h2;
            }
        }
        __syncthreads();  // B0': next x visible
    }
}

extern "C" void kernel_launch(void* const* d_in, const int* in_sizes, int n_in,
                              void* d_out, int out_size, void* d_ws, size_t ws_size,
                              hipStream_t stream) {
    const float* x          = (const float*)d_in[0];
    // d_in[1] = q_global: unused by the reference
    const float* w_qkv      = (const float*)d_in[2];
    const float* b_qkv      = (const float*)d_in[3];
    const float* w_proj     = (const float*)d_in[4];
    const float* b_proj     = (const float*)d_in[5];
    const float* bias_table = (const float*)d_in[6];
    const int*   rel_index  = (const int*)d_in[7];

    _Float16* ws = (_Float16*)d_ws;

    prepack<<<(WS_TOTAL + 255) / 256, 256, 0, stream>>>(w_qkv, b_qkv, w_proj,
                                                        bias_table, rel_index, ws);

    const int nwin = in_sizes[0] / (NWIN * CDIM);   // 16384
    const int wpb = 8;
    const int nblk = (nwin + wpb - 1) / wpb;        // 2048

    lwa_fused<<<nblk, 512, 0, stream>>>(x, ws, b_proj, (float*)d_out,
                                        nwin, wpb);
}